// Round 9
// baseline (64.446 us; speedup 1.0000x reference)
//
#include <hip/hip_runtime.h>

// Elementwise fuzzify: y[r, i] = clip(diag[r] * aug_r(x[i]) + b[r], 0, 1).
// R9: single-variable A/B vs R8 — loads nt -> cached. Everything else
// identical (ITERS=32, 128KB chunk in VGPRs, 1 block/CU, row-grouped 128KB
// contiguous cached-store runs). Rationale: R8 showed the nt path costs ~9%
// on stores; the nt LOAD may likewise throttle the read stream, which
// contends with row-0 writes. x is read once into registers, so caching it
// is harmless (33.5 MB << 256 MB LLC).

typedef float f32x4 __attribute__((ext_vector_type(4)));

constexpr int ITERS = 32;                   // float4s per thread (128 VGPRs)
constexpr int CHUNK_F4 = 256 * ITERS;       // 8192 float4s = 128 KB per block

__global__ __launch_bounds__(256, 1) void fuzzify_kernel(
    const float* __restrict__ x,
    const float* __restrict__ p_td_c,
    const float* __restrict__ p_td_s,
    const float* __restrict__ p_dl_s,
    const float* __restrict__ p_dl_cw,
    const float* __restrict__ p_dl_sw,
    const float* __restrict__ p_dl_ssw,
    float* __restrict__ out, int n)
{
    const float ms = 0.01f;
    const float td_c = p_td_c[0];
    const float td_s = fabsf(p_td_s[0] - ms) + ms;
    const float dl_s = fabsf(p_dl_s[0] - ms) + ms;

    const float slope_width = 1.0f / dl_s;
    const float cw  = fabsf(p_dl_cw[0]);
    const float sw  = fabsf(p_dl_sw[0]);
    const float ssw = fabsf(p_dl_ssw[0]);
    const float c_half  = 0.5f * cw;
    const float s_half  = 0.5f * sw;
    const float ss_half = 0.5f * ssw;

    const float d1 = dl_s * s_half + 1.0f;
    const float c1 = c_half + slope_width + s_half;
    const float d2 = dl_s * ss_half + 1.0f;
    const float c2 = c_half + 2.0f * slope_width + sw + ss_half;
    const float c3 = c_half + sw + 3.0f * slope_width + ssw;
    const float d3 = -dl_s * c3 + 1.0f;
    const float a  = td_c * td_s;

    // Row 2's aug = -x folded into slope: dl_s * (-x) == (-dl_s) * x.
    const float slope[9] = { -td_s, td_s, -dl_s, -dl_s, -dl_s, -dl_s, -dl_s, -dl_s, dl_s };
    const float bias[9]  = { 1.0f + a, -a, d3, d2, d1, dl_s * c_half + 1.0f, d1, d2, d3 };
    const float offs[9]  = { 0.0f, 0.0f, 0.0f, c2, c1, 0.0f, -c1, -c2, 0.0f };

    const int lane = threadIdx.x & 63;
    const int wav  = threadIdx.x >> 6;
    // wave w owns a contiguous 32KB span; block covers contiguous 128KB.
    const int i0 = blockIdx.x * CHUNK_F4 + wav * (64 * ITERS) + lane;

    const f32x4* __restrict__ x4 = (const f32x4*)x;

    // Load this thread's 32 float4s up front (independent -> deep MLP).
    f32x4 xv[ITERS];
    #pragma unroll
    for (int k = 0; k < ITERS; ++k)
        xv[k] = x4[i0 + k * 64];            // CACHED loads (A/B vs R8's nt)

    // For each output row: 32 consecutive 1KB wave-runs back-to-back
    // (32KB contiguous per wave, 128KB per block, per stream). Cached stores.
    #pragma unroll
    for (int r = 0; r < 9; ++r) {
        const float s  = slope[r];
        const float b  = bias[r];
        const float of = offs[r];
        const bool  is_abs = (r >= 3) && (r <= 7);
        float* __restrict__ orow = out + (size_t)r * (size_t)n;

        #pragma unroll
        for (int k = 0; k < ITERS; ++k) {
            f32x4 v = xv[k];
            f32x4 o;
            #pragma unroll
            for (int j = 0; j < 4; ++j) {
                float t = is_abs ? fabsf(v[j] + of) : v[j];
                float y = fmaf(s, t, b);
                o[j] = fminf(fmaxf(y, 0.0f), 1.0f);   // v_med3_f32
            }
            *(f32x4*)(orow + ((size_t)(i0 + k * 64) << 2)) = o;
        }
    }
}

extern "C" void kernel_launch(void* const* d_in, const int* in_sizes, int n_in,
                              void* d_out, int out_size, void* d_ws, size_t ws_size,
                              hipStream_t stream) {
    const float* x        = (const float*)d_in[0];
    const float* p_td_c   = (const float*)d_in[1];
    const float* p_td_s   = (const float*)d_in[2];
    const float* p_dl_s   = (const float*)d_in[3];
    const float* p_dl_cw  = (const float*)d_in[4];
    const float* p_dl_sw  = (const float*)d_in[5];
    const float* p_dl_ssw = (const float*)d_in[6];
    float* out = (float*)d_out;

    const int n = in_sizes[0];                 // 2^23
    const int n4 = n >> 2;                     // 2^21 float4s
    const int grid = n4 / CHUNK_F4;            // 256 blocks (exact) = 1/CU

    fuzzify_kernel<<<grid, 256, 0, stream>>>(
        x, p_td_c, p_td_s, p_dl_s, p_dl_cw, p_dl_sw, p_dl_ssw, out, n);
}

// Round 10
// 53.610 us; speedup vs baseline: 1.2021x; 1.2021x over previous
//
#include <hip/hip_runtime.h>

// Elementwise fuzzify: y[r, i] = clip(diag[r] * aug_r(x[i]) + b[r], 0, 1).
// R10: R8 config (nt loads + cached stores; R9 proved cached loads regress
// 10 us by polluting the L2 the stores need for write-combining) + raw
// s_barrier between row phases. Rationale: over 9 rows the block's 4 waves
// drift, so a CU's store stream mixes row regions 33.5 MB apart (the R3
// pathology). Raw s_barrier re-aligns waves at row granularity WITHOUT the
// vmcnt(0) drain __syncthreads would insert (stores stay in flight).

typedef float f32x4 __attribute__((ext_vector_type(4)));

constexpr int ITERS = 32;                   // float4s per thread (128 VGPRs)
constexpr int CHUNK_F4 = 256 * ITERS;       // 8192 float4s = 128 KB per block

__global__ __launch_bounds__(256, 1) void fuzzify_kernel(
    const float* __restrict__ x,
    const float* __restrict__ p_td_c,
    const float* __restrict__ p_td_s,
    const float* __restrict__ p_dl_s,
    const float* __restrict__ p_dl_cw,
    const float* __restrict__ p_dl_sw,
    const float* __restrict__ p_dl_ssw,
    float* __restrict__ out, int n)
{
    const float ms = 0.01f;
    const float td_c = p_td_c[0];
    const float td_s = fabsf(p_td_s[0] - ms) + ms;
    const float dl_s = fabsf(p_dl_s[0] - ms) + ms;

    const float slope_width = 1.0f / dl_s;
    const float cw  = fabsf(p_dl_cw[0]);
    const float sw  = fabsf(p_dl_sw[0]);
    const float ssw = fabsf(p_dl_ssw[0]);
    const float c_half  = 0.5f * cw;
    const float s_half  = 0.5f * sw;
    const float ss_half = 0.5f * ssw;

    const float d1 = dl_s * s_half + 1.0f;
    const float c1 = c_half + slope_width + s_half;
    const float d2 = dl_s * ss_half + 1.0f;
    const float c2 = c_half + 2.0f * slope_width + sw + ss_half;
    const float c3 = c_half + sw + 3.0f * slope_width + ssw;
    const float d3 = -dl_s * c3 + 1.0f;
    const float a  = td_c * td_s;

    // Row 2's aug = -x folded into slope: dl_s * (-x) == (-dl_s) * x.
    const float slope[9] = { -td_s, td_s, -dl_s, -dl_s, -dl_s, -dl_s, -dl_s, -dl_s, dl_s };
    const float bias[9]  = { 1.0f + a, -a, d3, d2, d1, dl_s * c_half + 1.0f, d1, d2, d3 };
    const float offs[9]  = { 0.0f, 0.0f, 0.0f, c2, c1, 0.0f, -c1, -c2, 0.0f };

    const int lane = threadIdx.x & 63;
    const int wav  = threadIdx.x >> 6;
    // wave w owns a contiguous 32KB span; block covers contiguous 128KB.
    const int i0 = blockIdx.x * CHUNK_F4 + wav * (64 * ITERS) + lane;

    const f32x4* __restrict__ x4 = (const f32x4*)x;

    // Load this thread's 32 float4s up front (nt: read-once, bypass the L2
    // the stores need for write-combining).
    f32x4 xv[ITERS];
    #pragma unroll
    for (int k = 0; k < ITERS; ++k)
        xv[k] = __builtin_nontemporal_load(&x4[i0 + k * 64]);

    // For each output row: 32 consecutive 1KB wave-runs back-to-back
    // (32KB/wave, 128KB/block contiguous). Cached stores. Barrier per row
    // keeps the block's 4 waves phase-aligned (no vmcnt drain).
    #pragma unroll
    for (int r = 0; r < 9; ++r) {
        const float s  = slope[r];
        const float b  = bias[r];
        const float of = offs[r];
        const bool  is_abs = (r >= 3) && (r <= 7);
        float* __restrict__ orow = out + (size_t)r * (size_t)n;

        #pragma unroll
        for (int k = 0; k < ITERS; ++k) {
            f32x4 v = xv[k];
            f32x4 o;
            #pragma unroll
            for (int j = 0; j < 4; ++j) {
                float t = is_abs ? fabsf(v[j] + of) : v[j];
                float y = fmaf(s, t, b);
                o[j] = fminf(fmaxf(y, 0.0f), 1.0f);   // v_med3_f32
            }
            *(f32x4*)(orow + ((size_t)(i0 + k * 64) << 2)) = o;
        }
        __builtin_amdgcn_s_barrier();   // align waves; stores stay in flight
    }
}

extern "C" void kernel_launch(void* const* d_in, const int* in_sizes, int n_in,
                              void* d_out, int out_size, void* d_ws, size_t ws_size,
                              hipStream_t stream) {
    const float* x        = (const float*)d_in[0];
    const float* p_td_c   = (const float*)d_in[1];
    const float* p_td_s   = (const float*)d_in[2];
    const float* p_dl_s   = (const float*)d_in[3];
    const float* p_dl_cw  = (const float*)d_in[4];
    const float* p_dl_sw  = (const float*)d_in[5];
    const float* p_dl_ssw = (const float*)d_in[6];
    float* out = (float*)d_out;

    const int n = in_sizes[0];                 // 2^23
    const int n4 = n >> 2;                     // 2^21 float4s
    const int grid = n4 / CHUNK_F4;            // 256 blocks (exact) = 1/CU

    fuzzify_kernel<<<grid, 256, 0, stream>>>(
        x, p_td_c, p_td_s, p_dl_s, p_dl_cw, p_dl_sw, p_dl_ssw, out, n);
}

// Round 11
// 53.077 us; speedup vs baseline: 1.2142x; 1.0100x over previous
//
#include <hip/hip_runtime.h>

// Elementwise fuzzify: y[r, i] = clip(diag[r] * aug_r(x[i]) + b[r], 0, 1).
// R11: occupancy A/B under cached-store regime. Same 128KB contiguous block
// chunk, 1 block/CU, nt loads + cached stores + per-row s_barrier (R10), but
// block=512 / ITERS=16 -> 8 waves/CU instead of 4. Hypothesis: with cached
// stores the L2 write-combines at block granularity, so per-wave run length
// (32KB->16KB) is absorbed, while 2x wave parallelism improves store-issue
// and bus-turnaround hiding.

typedef float f32x4 __attribute__((ext_vector_type(4)));

constexpr int ITERS = 16;                   // float4s per thread (64 VGPRs)
constexpr int BLOCK = 512;                  // 8 waves
constexpr int CHUNK_F4 = BLOCK * ITERS;     // 8192 float4s = 128 KB per block

__global__ __launch_bounds__(BLOCK, 1) void fuzzify_kernel(
    const float* __restrict__ x,
    const float* __restrict__ p_td_c,
    const float* __restrict__ p_td_s,
    const float* __restrict__ p_dl_s,
    const float* __restrict__ p_dl_cw,
    const float* __restrict__ p_dl_sw,
    const float* __restrict__ p_dl_ssw,
    float* __restrict__ out, int n)
{
    const float ms = 0.01f;
    const float td_c = p_td_c[0];
    const float td_s = fabsf(p_td_s[0] - ms) + ms;
    const float dl_s = fabsf(p_dl_s[0] - ms) + ms;

    const float slope_width = 1.0f / dl_s;
    const float cw  = fabsf(p_dl_cw[0]);
    const float sw  = fabsf(p_dl_sw[0]);
    const float ssw = fabsf(p_dl_ssw[0]);
    const float c_half  = 0.5f * cw;
    const float s_half  = 0.5f * sw;
    const float ss_half = 0.5f * ssw;

    const float d1 = dl_s * s_half + 1.0f;
    const float c1 = c_half + slope_width + s_half;
    const float d2 = dl_s * ss_half + 1.0f;
    const float c2 = c_half + 2.0f * slope_width + sw + ss_half;
    const float c3 = c_half + sw + 3.0f * slope_width + ssw;
    const float d3 = -dl_s * c3 + 1.0f;
    const float a  = td_c * td_s;

    // Row 2's aug = -x folded into slope: dl_s * (-x) == (-dl_s) * x.
    const float slope[9] = { -td_s, td_s, -dl_s, -dl_s, -dl_s, -dl_s, -dl_s, -dl_s, dl_s };
    const float bias[9]  = { 1.0f + a, -a, d3, d2, d1, dl_s * c_half + 1.0f, d1, d2, d3 };
    const float offs[9]  = { 0.0f, 0.0f, 0.0f, c2, c1, 0.0f, -c1, -c2, 0.0f };

    const int lane = threadIdx.x & 63;
    const int wav  = threadIdx.x >> 6;
    // wave w owns a contiguous 16KB span; block covers contiguous 128KB.
    const int i0 = blockIdx.x * CHUNK_F4 + wav * (64 * ITERS) + lane;

    const f32x4* __restrict__ x4 = (const f32x4*)x;

    // Load this thread's 16 float4s up front (nt: read-once, bypass the L2
    // the stores need for write-combining).
    f32x4 xv[ITERS];
    #pragma unroll
    for (int k = 0; k < ITERS; ++k)
        xv[k] = __builtin_nontemporal_load(&x4[i0 + k * 64]);

    // For each output row: 16 consecutive 1KB wave-runs back-to-back
    // (16KB/wave, 128KB/block contiguous). Cached stores. Barrier per row
    // keeps the block's 8 waves phase-aligned (no vmcnt drain).
    #pragma unroll
    for (int r = 0; r < 9; ++r) {
        const float s  = slope[r];
        const float b  = bias[r];
        const float of = offs[r];
        const bool  is_abs = (r >= 3) && (r <= 7);
        float* __restrict__ orow = out + (size_t)r * (size_t)n;

        #pragma unroll
        for (int k = 0; k < ITERS; ++k) {
            f32x4 v = xv[k];
            f32x4 o;
            #pragma unroll
            for (int j = 0; j < 4; ++j) {
                float t = is_abs ? fabsf(v[j] + of) : v[j];
                float y = fmaf(s, t, b);
                o[j] = fminf(fmaxf(y, 0.0f), 1.0f);   // v_med3_f32
            }
            *(f32x4*)(orow + ((size_t)(i0 + k * 64) << 2)) = o;
        }
        __builtin_amdgcn_s_barrier();   // align waves; stores stay in flight
    }
}

extern "C" void kernel_launch(void* const* d_in, const int* in_sizes, int n_in,
                              void* d_out, int out_size, void* d_ws, size_t ws_size,
                              hipStream_t stream) {
    const float* x        = (const float*)d_in[0];
    const float* p_td_c   = (const float*)d_in[1];
    const float* p_td_s   = (const float*)d_in[2];
    const float* p_dl_s   = (const float*)d_in[3];
    const float* p_dl_cw  = (const float*)d_in[4];
    const float* p_dl_sw  = (const float*)d_in[5];
    const float* p_dl_ssw = (const float*)d_in[6];
    float* out = (float*)d_out;

    const int n = in_sizes[0];                 // 2^23
    const int n4 = n >> 2;                     // 2^21 float4s
    const int grid = n4 / CHUNK_F4;            // 256 blocks (exact) = 1/CU

    fuzzify_kernel<<<grid, BLOCK, 0, stream>>>(
        x, p_td_c, p_td_s, p_dl_s, p_dl_cw, p_dl_sw, p_dl_ssw, out, n);
}